// Round 1
// baseline (449.023 us; speedup 1.0000x reference)
//
#include <hip/hip_runtime.h>

// Gather3d sparse-mode constants (from reference)
#define C_DIM 128
#define T_DIM 16
#define H_DIM 128
#define W_DIM 128
#define BH 16
#define BW 16
#define PAD_T 2
#define TT (T_DIM + PAD_T)          // 18
#define PLANE (BH * BW)             // 256 floats per (tt) plane
#define CHUNK (TT * PLANE)          // 4608 floats per (n,c)
#define CHUNK_F4 (CHUNK / 4)        // 1152 float4 per (n,c)

__global__ __launch_bounds__(256) void gather3d_kernel(
    const float* __restrict__ x,          // [C, T, H, W]
    const int*   __restrict__ active_idx, // [N, 2]
    float*       __restrict__ out)        // [N, C, TT, BH, BW]
{
    const int c = blockIdx.x;
    const int n = blockIdx.y;

    const int idx0 = active_idx[2 * n];
    const int idx1 = active_idx[2 * n + 1];

    const float* xc = x + (size_t)c * (T_DIM * H_DIM * W_DIM);
    float4* outb = (float4*)(out + ((size_t)n * C_DIM + c) * (size_t)CHUNK);

    for (int w = threadIdx.x; w < CHUNK_F4; w += 256) {
        const int tt    = w >> 6;        // / 64 float4 per plane
        const int local = w & 63;
        const int i     = local >> 2;    // row within 16x16 block
        const int j     = (local & 3) << 2;

        float4 v;
        if (tt < PAD_T) {
            v = make_float4(0.f, 0.f, 0.f, 0.f);
        } else {
            const float* src = xc
                + ((size_t)(tt - PAD_T) * H_DIM + (size_t)(idx0 + i)) * W_DIM
                + idx1 + j;
            v.x = src[0];
            v.y = src[1];
            v.z = src[2];
            v.w = src[3];
        }
        outb[w] = v;
    }
}

extern "C" void kernel_launch(void* const* d_in, const int* in_sizes, int n_in,
                              void* d_out, int out_size, void* d_ws, size_t ws_size,
                              hipStream_t stream) {
    const float* x   = (const float*)d_in[0];
    const int*   idx = (const int*)d_in[1];
    float*       out = (float*)d_out;

    const int N = in_sizes[1] / 2;   // 128 active indices

    dim3 grid(C_DIM, N);
    dim3 block(256);
    gather3d_kernel<<<grid, block, 0, stream>>>(x, idx, out);
}

// Round 2
// 436.881 us; speedup vs baseline: 1.0278x; 1.0278x over previous
//
#include <hip/hip_runtime.h>

// Gather3d sparse-mode constants (from reference)
#define C_DIM 128
#define T_DIM 16
#define H_DIM 128
#define W_DIM 128
#define PAD_T 2
#define TT (T_DIM + PAD_T)          // 18 planes per (n,c) chunk
#define CPB 2                       // channels per block
#define F4_PER_CHUNK (TT * 64)      // 1152 float4 per (n,c)
#define F4_PER_BLOCK (CPB * F4_PER_CHUNK)   // 2304
#define ITERS (F4_PER_BLOCK / 256)  // 9 exact iterations, no tail

// 4-byte-aligned float4: gfx950 VMEM supports misaligned dwordx4, so the
// compiler keeps a single global_load_dwordx4 even at align(4).
typedef float f4u __attribute__((ext_vector_type(4), aligned(4)));
typedef float f4a __attribute__((ext_vector_type(4), aligned(16)));

__global__ __launch_bounds__(256) void gather3d_kernel(
    const float* __restrict__ x,          // [C, T, H, W]
    const int*   __restrict__ active_idx, // [N, 2]
    float*       __restrict__ out)        // [N, C, TT, 16, 16]
{
    const int cbase = blockIdx.x * CPB;
    const int n     = blockIdx.y;

    const int idx0 = active_idx[2 * n];
    const int idx1 = active_idx[2 * n + 1];

    // chunks for cbase..cbase+CPB-1 are contiguous in out
    f4a* outb = (f4a*)(out + ((size_t)n * C_DIM + cbase) * (size_t)(TT * 256));

    #pragma unroll
    for (int it = 0; it < ITERS; ++it) {
        const int w     = threadIdx.x + it * 256;
        const int plane = w >> 6;            // 0..35, uniform per wave
        const int local = w & 63;
        const int cl    = (plane >= TT) ? 1 : 0;
        const int tt    = plane - cl * TT;   // 0..17, uniform per wave
        const int i     = local >> 2;        // row in 16x16 block
        const int j     = (local & 3) << 2;  // 4-float group in row

        f4a v = {0.f, 0.f, 0.f, 0.f};
        if (tt >= PAD_T) {                   // wave-uniform branch
            const float* src = x
                + (((size_t)(cbase + cl) * T_DIM + (size_t)(tt - PAD_T)) * H_DIM
                   + (size_t)(idx0 + i)) * W_DIM
                + idx1 + j;
            v = *(const f4u*)src;            // single global_load_dwordx4
        }
        __builtin_nontemporal_store(v, outb + w);
    }
}

extern "C" void kernel_launch(void* const* d_in, const int* in_sizes, int n_in,
                              void* d_out, int out_size, void* d_ws, size_t ws_size,
                              hipStream_t stream) {
    const float* x   = (const float*)d_in[0];
    const int*   idx = (const int*)d_in[1];
    float*       out = (float*)d_out;

    const int N = in_sizes[1] / 2;   // 128 active indices

    dim3 grid(C_DIM / CPB, N);
    dim3 block(256);
    gather3d_kernel<<<grid, block, 0, stream>>>(x, idx, out);
}